// Round 1
// baseline (339.212 us; speedup 1.0000x reference)
//
#include <hip/hip_runtime.h>
#include <hip/hip_bf16.h>

#define BS   16384
#define NC   2000
#define EMB  512
#define NAUX 5

typedef __bf16 bf16x8 __attribute__((ext_vector_type(8)));
typedef float  f32x4  __attribute__((ext_vector_type(4)));

// ---------------------------------------------------------------------------
// Kernel 1: row-normalize features (rows [0,BS)) and word_embed (rows [BS,BS+NC))
// into bf16. One wave per row, 8 floats per lane.
// ---------------------------------------------------------------------------
__global__ __launch_bounds__(64) void norm_kernel(
    const float* __restrict__ feat, const float* __restrict__ wemb,
    __bf16* __restrict__ fn, __bf16* __restrict__ wn)
{
    const int lane = threadIdx.x;
    const int row  = blockIdx.x;
    const float* src;
    __bf16* dst;
    if (row < BS) { src = feat + (size_t)row * EMB;        dst = fn + (size_t)row * EMB; }
    else          { src = wemb + (size_t)(row - BS) * EMB; dst = wn + (size_t)(row - BS) * EMB; }

    float4 x0 = ((const float4*)src)[lane * 2];
    float4 x1 = ((const float4*)src)[lane * 2 + 1];
    float ss = x0.x*x0.x + x0.y*x0.y + x0.z*x0.z + x0.w*x0.w
             + x1.x*x1.x + x1.y*x1.y + x1.z*x1.z + x1.w*x1.w;
    #pragma unroll
    for (int m = 1; m < 64; m <<= 1) ss += __shfl_xor(ss, m, 64);
    const float scale = 1.0f / fmaxf(sqrtf(ss), 1e-12f);

    bf16x8 o;
    o[0] = (__bf16)(x0.x * scale); o[1] = (__bf16)(x0.y * scale);
    o[2] = (__bf16)(x0.z * scale); o[3] = (__bf16)(x0.w * scale);
    o[4] = (__bf16)(x1.x * scale); o[5] = (__bf16)(x1.y * scale);
    o[6] = (__bf16)(x1.z * scale); o[7] = (__bf16)(x1.w * scale);
    ((bf16x8*)dst)[lane] = o;
}

// ---------------------------------------------------------------------------
// Kernel 2: fused GEMM (f_n @ w_n^T) + per-row sum(exp(logit-20)) + argmax.
// Block = 256 threads (4 waves) handles 16 rows. Waves split the 125 col-tiles
// of 16. A-panel (16x512) lives in 64 VGPRs per wave. B frags streamed from
// global (w_n is 2 MB -> L2 resident).
// mfma_f32_16x16x32_bf16 layouts (HW-verified per guide):
//   A frag: lane holds A[m=lane&15][k=(lane>>4)*8 + j], j=0..7  (16B contiguous)
//   B frag: lane holds B[k=(lane>>4)*8+j][n=lane&15] = w_n[n][k] (16B contiguous)
//   C/D:    col = lane&15, row = (lane>>4)*4 + reg
// ---------------------------------------------------------------------------
__global__ __launch_bounds__(256) void main_kernel(
    const __bf16* __restrict__ fn, const __bf16* __restrict__ wn,
    float* __restrict__ lse_out, int* __restrict__ amax_out)
{
    const int lane = threadIdx.x & 63;
    const int wv   = threadIdx.x >> 6;
    const int quad = lane >> 4;
    const int mrow = lane & 15;
    const int rowBase = blockIdx.x * 16;

    __shared__ float s_es[4][16];
    __shared__ float s_mv[4][16];
    __shared__ int   s_mi[4][16];

    // Load A panel: 16 frags of 8 bf16 (64 VGPRs)
    const bf16x8* fp = (const bf16x8*)fn + (size_t)(rowBase + mrow) * (EMB / 8) + quad;
    bf16x8 a[16];
    #pragma unroll
    for (int kc = 0; kc < 16; ++kc) a[kc] = fp[kc * 4];

    float esum[4] = {0.f, 0.f, 0.f, 0.f};
    float mval[4] = {-1e30f, -1e30f, -1e30f, -1e30f};
    int   midx[4] = {0, 0, 0, 0};

    for (int t = wv; t < NC / 16; t += 4) {
        f32x4 acc = {0.f, 0.f, 0.f, 0.f};
        const bf16x8* wp = (const bf16x8*)wn + (size_t)(t * 16 + mrow) * (EMB / 8) + quad;
        #pragma unroll
        for (int kc = 0; kc < 16; ++kc) {
            bf16x8 b = wp[kc * 4];
            acc = __builtin_amdgcn_mfma_f32_16x16x32_bf16(a[kc], b, acc, 0, 0, 0);
        }
        const int col = t * 16 + mrow;  // C-layout col for this lane
        #pragma unroll
        for (int r = 0; r < 4; ++r) {
            float v = acc[r];  // cosine; logit = 20*v; exp(logit-20) = 2^((v-1)*20*log2(e))
            esum[r] += exp2f((v - 1.0f) * 28.853900817779268f);
            bool g = v > mval[r];  // strictly greater keeps first occurrence (cols increase)
            mval[r] = g ? v : mval[r];
            midx[r] = g ? col : midx[r];
        }
    }

    // Intra-wave reduction over the 16 lanes of each quad (each row's cols)
    #pragma unroll
    for (int r = 0; r < 4; ++r) {
        #pragma unroll
        for (int m = 1; m < 16; m <<= 1) {
            esum[r] += __shfl_xor(esum[r], m, 64);
            float v2 = __shfl_xor(mval[r], m, 64);
            int   i2 = __shfl_xor(midx[r], m, 64);
            bool take = (v2 > mval[r]) || (v2 == mval[r] && i2 < midx[r]);
            mval[r] = take ? v2 : mval[r];
            midx[r] = take ? i2 : midx[r];
        }
    }

    // Cross-wave merge via LDS
    if (mrow == 0) {
        #pragma unroll
        for (int r = 0; r < 4; ++r) {
            int row = quad * 4 + r;
            s_es[wv][row] = esum[r];
            s_mv[wv][row] = mval[r];
            s_mi[wv][row] = midx[r];
        }
    }
    __syncthreads();
    if (threadIdx.x < 16) {
        int row = threadIdx.x;
        float es = 0.f;
        float mv = -1e30f;
        int   mi = 0x7fffffff;
        #pragma unroll
        for (int w = 0; w < 4; ++w) {
            es += s_es[w][row];
            float v2 = s_mv[w][row];
            int   i2 = s_mi[w][row];
            if (v2 > mv || (v2 == mv && i2 < mi)) { mv = v2; mi = i2; }
        }
        lse_out[rowBase + row]  = 20.0f + logf(es);
        amax_out[rowBase + row] = mi;
    }
}

// ---------------------------------------------------------------------------
// Kernel 3: gather pred[i,label[i]] and sum_j pred[i,aux[i,j]] (6 length-512
// dots per row). One wave per row.
// ---------------------------------------------------------------------------
__global__ __launch_bounds__(256) void gather_kernel(
    const __bf16* __restrict__ fn, const __bf16* __restrict__ wn,
    const int* __restrict__ label, const int* __restrict__ aux,
    float* __restrict__ tgt, float* __restrict__ auxs)
{
    const int lane = threadIdx.x & 63;
    const int row  = blockIdx.x * 4 + (threadIdx.x >> 6);

    bf16x8 f8 = *((const bf16x8*)fn + (size_t)row * (EMB / 8) + lane);
    float fv[8];
    #pragma unroll
    for (int j = 0; j < 8; ++j) fv[j] = (float)f8[j];

    int cols[6];
    cols[0] = label[row];
    #pragma unroll
    for (int j = 0; j < NAUX; ++j) cols[j + 1] = aux[row * NAUX + j];

    float res[6];
    #pragma unroll
    for (int c = 0; c < 6; ++c) {
        bf16x8 w8 = *((const bf16x8*)wn + (size_t)cols[c] * (EMB / 8) + lane);
        float d = 0.f;
        #pragma unroll
        for (int j = 0; j < 8; ++j) d += fv[j] * (float)w8[j];
        #pragma unroll
        for (int m = 1; m < 64; m <<= 1) d += __shfl_xor(d, m, 64);
        res[c] = d;
    }
    if (lane == 0) {
        tgt[row]  = res[0] * 20.0f;
        auxs[row] = (res[1] + res[2] + res[3] + res[4] + res[5]) * 20.0f;
    }
}

// ---------------------------------------------------------------------------
// Kernel 4: final reduction to (loss, acc).
// loss_i = lse_i - 0.95*tgt_i - 0.01*auxsum_i
//   (0.5*((-t+lse) + (-(1-a)t + lse - (a/5)*auxsum)), a=0.1)
// ---------------------------------------------------------------------------
__global__ __launch_bounds__(256) void finalize_kernel(
    const float* __restrict__ lse, const float* __restrict__ tgt,
    const float* __restrict__ auxs, const int* __restrict__ amax,
    const int* __restrict__ label, float* __restrict__ out)
{
    float s = 0.f, c = 0.f;
    for (int i = threadIdx.x; i < BS; i += 256) {
        s += lse[i] - 0.95f * tgt[i] - 0.01f * auxs[i];
        c += (amax[i] == label[i]) ? 1.0f : 0.0f;
    }
    #pragma unroll
    for (int m = 1; m < 64; m <<= 1) {
        s += __shfl_xor(s, m, 64);
        c += __shfl_xor(c, m, 64);
    }
    __shared__ float ls[4], lc[4];
    const int wv = threadIdx.x >> 6;
    if ((threadIdx.x & 63) == 0) { ls[wv] = s; lc[wv] = c; }
    __syncthreads();
    if (threadIdx.x == 0) {
        out[0] = (ls[0] + ls[1] + ls[2] + ls[3]) / (float)BS;
        out[1] = (lc[0] + lc[1] + lc[2] + lc[3]) / (float)BS;
    }
}

// ---------------------------------------------------------------------------
// Workspace layout (bytes):
//   fn   : 0          .. 16777216   (16384*512*2)
//   wn   : 16777216   .. 18825216   (2000*512*2)
//   lse  : 18825216   .. 18890752   (16384*4)
//   tgt  : 18890752   .. 18956288
//   auxs : 18956288   .. 19021824
//   amax : 19021824   .. 19087360
// ---------------------------------------------------------------------------
extern "C" void kernel_launch(void* const* d_in, const int* in_sizes, int n_in,
                              void* d_out, int out_size, void* d_ws, size_t ws_size,
                              hipStream_t stream)
{
    const float* feat  = (const float*)d_in[0];
    const float* wemb  = (const float*)d_in[1];
    const int*   label = (const int*)d_in[2];
    const int*   aux   = (const int*)d_in[3];

    char* ws = (char*)d_ws;
    __bf16* fn   = (__bf16*)(ws);
    __bf16* wn   = (__bf16*)(ws + 16777216);
    float*  lse  = (float*)(ws + 18825216);
    float*  tgt  = (float*)(ws + 18890752);
    float*  auxs = (float*)(ws + 18956288);
    int*    amax = (int*)(ws + 19021824);
    float*  out  = (float*)d_out;

    hipLaunchKernelGGL(norm_kernel, dim3(BS + NC), dim3(64), 0, stream, feat, wemb, fn, wn);
    hipLaunchKernelGGL(main_kernel, dim3(BS / 16), dim3(256), 0, stream, fn, wn, lse, amax);
    hipLaunchKernelGGL(gather_kernel, dim3(BS / 4), dim3(256), 0, stream,
                       fn, wn, label, aux, tgt, auxs);
    hipLaunchKernelGGL(finalize_kernel, dim3(1), dim3(256), 0, stream,
                       lse, tgt, auxs, amax, label, out);
}

// Round 3
// 238.485 us; speedup vs baseline: 1.4224x; 1.4224x over previous
//
#include <hip/hip_runtime.h>
#include <hip/hip_bf16.h>
#include <stdint.h>

#define BS   16384
#define NC   2000
#define EMB  512
#define NAUX 5
#define NTILE 125            // NC/16 exact
#define CHUNKS 4

typedef __bf16 bf16x8 __attribute__((ext_vector_type(8)));
typedef float  f32x4  __attribute__((ext_vector_type(4)));

// ---------------------------------------------------------------------------
// Kernel 1: row-normalize features (rows [0,BS)) and word_embed ([BS,BS+NC))
// into bf16. One wave per row, 4 waves per block.
// ---------------------------------------------------------------------------
__global__ __launch_bounds__(256) void norm_kernel(
    const float* __restrict__ feat, const float* __restrict__ wemb,
    __bf16* __restrict__ fn, __bf16* __restrict__ wn)
{
    const int lane = threadIdx.x & 63;
    const int row  = blockIdx.x * 4 + (threadIdx.x >> 6);
    const float* src;
    __bf16* dst;
    if (row < BS) { src = feat + (size_t)row * EMB;        dst = fn + (size_t)row * EMB; }
    else          { src = wemb + (size_t)(row - BS) * EMB; dst = wn + (size_t)(row - BS) * EMB; }

    float4 x0 = ((const float4*)src)[lane * 2];
    float4 x1 = ((const float4*)src)[lane * 2 + 1];
    float ss = x0.x*x0.x + x0.y*x0.y + x0.z*x0.z + x0.w*x0.w
             + x1.x*x1.x + x1.y*x1.y + x1.z*x1.z + x1.w*x1.w;
    #pragma unroll
    for (int m = 1; m < 64; m <<= 1) ss += __shfl_xor(ss, m, 64);
    const float scale = 1.0f / fmaxf(sqrtf(ss), 1e-12f);

    bf16x8 o;
    o[0] = (__bf16)(x0.x * scale); o[1] = (__bf16)(x0.y * scale);
    o[2] = (__bf16)(x0.z * scale); o[3] = (__bf16)(x0.w * scale);
    o[4] = (__bf16)(x1.x * scale); o[5] = (__bf16)(x1.y * scale);
    o[6] = (__bf16)(x1.z * scale); o[7] = (__bf16)(x1.w * scale);
    ((bf16x8*)dst)[lane] = o;
}

// ---------------------------------------------------------------------------
// Kernel 2: fused GEMM + per-row sum(exp(logit-20)) + packed argmax.
// Block = 4 waves; each wave owns TWO 16-row A panels (32 rows, 128 VGPRs)
// and shares every B fragment between them (2 MFMAs per B load -> half the
// B traffic per FLOP, two independent acc chains). 4-way col-chunk split by
// blockIdx&3; B read directly from global (wn = 2 MB, L2-resident).
// mfma_f32_16x16x32_bf16 verified layouts:
//   A frag: lane(m=lane&15, q=lane>>4) holds A[m][q*8+j]   (16B contiguous)
//   B frag: lane(n=lane&15, q)         holds B[q*8+j][n] = wn[n][q*8+j]
//   C/D:    col = lane&15, row = q*4 + reg
// ---------------------------------------------------------------------------
__global__ __launch_bounds__(256, 2) void main_kernel(
    const __bf16* __restrict__ fn, const __bf16* __restrict__ wn,
    float* __restrict__ es_part, unsigned* __restrict__ key_part)
{
    const int lane  = threadIdx.x & 63;
    const int quad  = lane >> 4;
    const int nidx  = lane & 15;
    const int wv    = threadIdx.x >> 6;
    const int chunk = blockIdx.x & 3;
    const int rowLo = (blockIdx.x >> 2) * 128 + wv * 32;  // panels [rowLo,+16) and [rowLo+16,+16)

    const int t0 = (NTILE * chunk) / CHUNKS;
    const int t1 = (NTILE * (chunk + 1)) / CHUNKS;

    // Two A panels: 32 rows x 512 cols, 128 VGPRs/lane
    const bf16x8* fpL = (const bf16x8*)fn + (size_t)(rowLo + nidx) * (EMB / 8) + quad;
    const bf16x8* fpH = fpL + 16 * (EMB / 8);
    bf16x8 aL[16], aH[16];
    #pragma unroll
    for (int kc = 0; kc < 16; ++kc) { aL[kc] = fpL[kc * 4]; aH[kc] = fpH[kc * 4]; }

    float    esL[4] = {0.f, 0.f, 0.f, 0.f}, esH[4] = {0.f, 0.f, 0.f, 0.f};
    unsigned kmL[4] = {0u, 0u, 0u, 0u},    kmH[4] = {0u, 0u, 0u, 0u};

    for (int t = t0; t < t1; ++t) {
        const bf16x8* wp = (const bf16x8*)wn + (size_t)(t * 16 + nidx) * (EMB / 8) + quad;
        f32x4 accL = {0.f, 0.f, 0.f, 0.f};
        f32x4 accH = {0.f, 0.f, 0.f, 0.f};
        #pragma unroll
        for (int kc = 0; kc < 16; ++kc) {
            bf16x8 b = wp[kc * 4];
            accL = __builtin_amdgcn_mfma_f32_16x16x32_bf16(aL[kc], b, accL, 0, 0, 0);
            accH = __builtin_amdgcn_mfma_f32_16x16x32_bf16(aH[kc], b, accH, 0, 0, 0);
        }

        const unsigned colenc = 2047u - (unsigned)(t * 16 + nidx);
        #pragma unroll
        for (int r = 0; r < 4; ++r) {
            float vL = accL[r], vH = accH[r];   // cosine; logit = 20v
            esL[r] += exp2f((vL - 1.0f) * 28.853900817779268f);
            esH[r] += exp2f((vH - 1.0f) * 28.853900817779268f);
            unsigned uL = __float_as_uint(vL);
            unsigned kL = uL ^ (unsigned)(((int)uL >> 31) | 0x80000000);
            unsigned pL = (kL & 0xFFFFF800u) | colenc;   // bigger v, then smaller col
            kmL[r] = pL > kmL[r] ? pL : kmL[r];
            unsigned uH = __float_as_uint(vH);
            unsigned kH = uH ^ (unsigned)(((int)uH >> 31) | 0x80000000);
            unsigned pH = (kH & 0xFFFFF800u) | colenc;
            kmH[r] = pH > kmH[r] ? pH : kmH[r];
        }
    }

    // Reduce over the 16 lanes (nidx) sharing each (quad, r) output row
    #pragma unroll
    for (int r = 0; r < 4; ++r) {
        #pragma unroll
        for (int m = 1; m < 16; m <<= 1) {
            esL[r] += __shfl_xor(esL[r], m, 64);
            esH[r] += __shfl_xor(esH[r], m, 64);
            unsigned x = __shfl_xor(kmL[r], m, 64); kmL[r] = x > kmL[r] ? x : kmL[r];
            unsigned y = __shfl_xor(kmH[r], m, 64); kmH[r] = y > kmH[r] ? y : kmH[r];
        }
    }
    if (nidx == 0) {
        #pragma unroll
        for (int r = 0; r < 4; ++r) {
            const int rl = rowLo + quad * 4 + r;
            es_part[chunk * BS + rl]       = esL[r];
            key_part[chunk * BS + rl]      = kmL[r];
            es_part[chunk * BS + rl + 16]  = esH[r];
            key_part[chunk * BS + rl + 16] = kmH[r];
        }
    }
}

// ---------------------------------------------------------------------------
// Kernel 3: gather pred[i,label[i]] and sum_j pred[i,aux[i,j]]. One wave/row.
// ---------------------------------------------------------------------------
__global__ __launch_bounds__(256) void gather_kernel(
    const __bf16* __restrict__ fn, const __bf16* __restrict__ wn,
    const int* __restrict__ label, const int* __restrict__ aux,
    float* __restrict__ tgt, float* __restrict__ auxs)
{
    const int lane = threadIdx.x & 63;
    const int row  = blockIdx.x * 4 + (threadIdx.x >> 6);

    bf16x8 f8 = *((const bf16x8*)fn + (size_t)row * (EMB / 8) + lane);
    float fv[8];
    #pragma unroll
    for (int j = 0; j < 8; ++j) fv[j] = (float)f8[j];

    int cols[6];
    cols[0] = label[row];
    #pragma unroll
    for (int j = 0; j < NAUX; ++j) cols[j + 1] = aux[row * NAUX + j];

    float res[6];
    #pragma unroll
    for (int c = 0; c < 6; ++c) {
        bf16x8 w8 = *((const bf16x8*)wn + (size_t)cols[c] * (EMB / 8) + lane);
        float d = 0.f;
        #pragma unroll
        for (int j = 0; j < 8; ++j) d += fv[j] * (float)w8[j];
        #pragma unroll
        for (int m = 1; m < 64; m <<= 1) d += __shfl_xor(d, m, 64);
        res[c] = d;
    }
    if (lane == 0) {
        tgt[row]  = res[0] * 20.0f;
        auxs[row] = (res[1] + res[2] + res[3] + res[4] + res[5]) * 20.0f;
    }
}

// ---------------------------------------------------------------------------
// Kernel 4: per-row combine of 4 chunk partials -> loss_i, acc_i; block-reduce.
// loss_i = lse_i - 0.95*tgt_i - 0.01*auxsum_i
// ---------------------------------------------------------------------------
__global__ __launch_bounds__(256) void fin1_kernel(
    const float* __restrict__ es_part, const unsigned* __restrict__ key_part,
    const float* __restrict__ tgt, const float* __restrict__ auxs,
    const int* __restrict__ label, float* __restrict__ blk)
{
    const int row = blockIdx.x * 256 + threadIdx.x;
    float es = es_part[row] + es_part[BS + row] + es_part[2 * BS + row] + es_part[3 * BS + row];
    unsigned k0 = key_part[row],          k1 = key_part[BS + row];
    unsigned k2 = key_part[2 * BS + row], k3 = key_part[3 * BS + row];
    unsigned k = k0 > k1 ? k0 : k1;
    k = k > k2 ? k : k2;
    k = k > k3 ? k : k3;
    const int amax = 2047 - (int)(k & 0x7FFu);

    float loss = 20.0f + logf(es) - 0.95f * tgt[row] - 0.01f * auxs[row];
    float acc  = (amax == label[row]) ? 1.0f : 0.0f;

    #pragma unroll
    for (int m = 1; m < 64; m <<= 1) {
        loss += __shfl_xor(loss, m, 64);
        acc  += __shfl_xor(acc, m, 64);
    }
    __shared__ float sl[4], sa[4];
    const int wv = threadIdx.x >> 6;
    if ((threadIdx.x & 63) == 0) { sl[wv] = loss; sa[wv] = acc; }
    __syncthreads();
    if (threadIdx.x == 0) {
        blk[blockIdx.x]      = sl[0] + sl[1] + sl[2] + sl[3];
        blk[64 + blockIdx.x] = sa[0] + sa[1] + sa[2] + sa[3];
    }
}

__global__ __launch_bounds__(64) void fin2_kernel(
    const float* __restrict__ blk, float* __restrict__ out)
{
    float l = blk[threadIdx.x];
    float a = blk[64 + threadIdx.x];
    #pragma unroll
    for (int m = 1; m < 64; m <<= 1) {
        l += __shfl_xor(l, m, 64);
        a += __shfl_xor(a, m, 64);
    }
    if (threadIdx.x == 0) {
        out[0] = l / (float)BS;
        out[1] = a / (float)BS;
    }
}

// ---------------------------------------------------------------------------
// Workspace layout (bytes):
//   fn       @ 0         (16,777,216)
//   wn       @ 16777216  ( 2,048,000)
//   es_part  @ 18825216  (   262,144)  [4][BS] f32
//   key_part @ 19087360  (   262,144)  [4][BS] u32
//   tgt      @ 19349504  (    65,536)
//   auxs     @ 19415040  (    65,536)
//   blk      @ 19480576  (       512)  [2][64] f32
// ---------------------------------------------------------------------------
extern "C" void kernel_launch(void* const* d_in, const int* in_sizes, int n_in,
                              void* d_out, int out_size, void* d_ws, size_t ws_size,
                              hipStream_t stream)
{
    const float* feat  = (const float*)d_in[0];
    const float* wemb  = (const float*)d_in[1];
    const int*   label = (const int*)d_in[2];
    const int*   aux   = (const int*)d_in[3];

    char* ws = (char*)d_ws;
    __bf16*   fn   = (__bf16*)(ws);
    __bf16*   wn   = (__bf16*)(ws + 16777216);
    float*    es   = (float*)(ws + 18825216);
    unsigned* key  = (unsigned*)(ws + 19087360);
    float*    tgt  = (float*)(ws + 19349504);
    float*    auxs = (float*)(ws + 19415040);
    float*    blk  = (float*)(ws + 19480576);
    float*    out  = (float*)d_out;

    hipLaunchKernelGGL(norm_kernel, dim3((BS + NC) / 4), dim3(256), 0, stream,
                       feat, wemb, fn, wn);
    hipLaunchKernelGGL(main_kernel, dim3((BS / 128) * CHUNKS), dim3(256), 0, stream,
                       fn, wn, es, key);
    hipLaunchKernelGGL(gather_kernel, dim3(BS / 4), dim3(256), 0, stream,
                       fn, wn, label, aux, tgt, auxs);
    hipLaunchKernelGGL(fin1_kernel, dim3(BS / 256), dim3(256), 0, stream,
                       es, key, tgt, auxs, label, blk);
    hipLaunchKernelGGL(fin2_kernel, dim3(1), dim3(64), 0, stream, blk, out);
}

// Round 4
// 170.762 us; speedup vs baseline: 1.9865x; 1.3966x over previous
//
#include <hip/hip_runtime.h>
#include <hip/hip_bf16.h>
#include <stdint.h>

#define BS   16384
#define NC   2000
#define NCP  2048            // padded N (wn zero-filled rows 2000..2047)
#define EMB  512
#define NAUX 5
#define NCHUNK 32            // es/key partial chunks: nTile*2 + wvN

typedef __bf16 bf16x8 __attribute__((ext_vector_type(8)));
typedef float  f32x4  __attribute__((ext_vector_type(4)));

#define LDSS 72              // LDS row stride in elements (144 B: +16B pad -> 2-way = free)

// ---------------------------------------------------------------------------
// Kernel 1: row-normalize features (rows [0,BS)) and word_embed ([BS,BS+NC))
// into bf16; zero-fill wn padding rows [NC,NCP). One wave per row.
// ---------------------------------------------------------------------------
__global__ __launch_bounds__(256) void norm_kernel(
    const float* __restrict__ feat, const float* __restrict__ wemb,
    __bf16* __restrict__ fn, __bf16* __restrict__ wn)
{
    const int lane = threadIdx.x & 63;
    const int row  = blockIdx.x * 4 + (threadIdx.x >> 6);

    if (row >= BS + NC) {  // padding rows of wn -> zeros (masked in epilogue)
        bf16x8 z = {};
        ((bf16x8*)(wn + (size_t)(row - BS) * EMB))[lane] = z;
        return;
    }
    const float* src;
    __bf16* dst;
    if (row < BS) { src = feat + (size_t)row * EMB;        dst = fn + (size_t)row * EMB; }
    else          { src = wemb + (size_t)(row - BS) * EMB; dst = wn + (size_t)(row - BS) * EMB; }

    float4 x0 = ((const float4*)src)[lane * 2];
    float4 x1 = ((const float4*)src)[lane * 2 + 1];
    float ss = x0.x*x0.x + x0.y*x0.y + x0.z*x0.z + x0.w*x0.w
             + x1.x*x1.x + x1.y*x1.y + x1.z*x1.z + x1.w*x1.w;
    #pragma unroll
    for (int m = 1; m < 64; m <<= 1) ss += __shfl_xor(ss, m, 64);
    const float scale = 1.0f / fmaxf(sqrtf(ss), 1e-12f);

    bf16x8 o;
    o[0] = (__bf16)(x0.x * scale); o[1] = (__bf16)(x0.y * scale);
    o[2] = (__bf16)(x0.z * scale); o[3] = (__bf16)(x0.w * scale);
    o[4] = (__bf16)(x1.x * scale); o[5] = (__bf16)(x1.y * scale);
    o[6] = (__bf16)(x1.z * scale); o[7] = (__bf16)(x1.w * scale);
    ((bf16x8*)dst)[lane] = o;
}

// ---------------------------------------------------------------------------
// Kernel 2: m93-structure GEMM (128x128 tile, LDS-staged A and B, 4 waves in
// 2x2, 4x4 MFMA accumulators per wave) + fused exp-sum / packed-argmax
// epilogue writing 32-chunk per-row partials.
// mfma_f32_16x16x32_bf16 verified layouts:
//   A frag: lane(m=lane&15, q=lane>>4) holds A[m][q*8+j]
//   B frag: lane(n=lane&15, q)         holds B[q*8+j][n] = wn[n][q*8+j]
//   C/D:    col(n) = lane&15, row(m) = q*4 + reg
// ---------------------------------------------------------------------------
__global__ __launch_bounds__(256, 2) void main_kernel(
    const __bf16* __restrict__ fn, const __bf16* __restrict__ wn,
    float* __restrict__ es_part, unsigned* __restrict__ key_part)
{
    __shared__ __bf16 As[128 * LDSS];
    __shared__ __bf16 Bsh[128 * LDSS];

    const int tid   = threadIdx.x;
    const int lane  = tid & 63;
    const int l15   = lane & 15;
    const int quad  = lane >> 4;
    const int wv    = tid >> 6;
    const int wvM   = wv >> 1;
    const int wvN   = wv & 1;
    const int mTile = blockIdx.x >> 4;   // 128 m-tiles
    const int nTile = blockIdx.x & 15;   // 16 n-tiles (N padded to 2048)

    const int sRow = tid >> 3;           // 0..31  (staging row within pass)
    const int sCol = (tid & 7) * 8;      // element col offset 0..56

    f32x4 acc[4][4] = {};

    const __bf16* fbase = fn + (size_t)mTile * 128 * EMB;
    const __bf16* wbase = wn + (size_t)nTile * 128 * EMB;

    for (int kk = 0; kk < EMB; kk += 64) {
        __syncthreads();                 // previous iter's readers done
        #pragma unroll
        for (int p = 0; p < 4; ++p) {
            const int r = sRow + p * 32;
            *(bf16x8*)&As [r * LDSS + sCol] = *(const bf16x8*)&fbase[(size_t)r * EMB + kk + sCol];
            *(bf16x8*)&Bsh[r * LDSS + sCol] = *(const bf16x8*)&wbase[(size_t)r * EMB + kk + sCol];
        }
        __syncthreads();                 // staged data visible

        #pragma unroll
        for (int kc = 0; kc < 2; ++kc) {
            bf16x8 aF[4], bF[4];
            #pragma unroll
            for (int i = 0; i < 4; ++i) {
                aF[i] = *(const bf16x8*)&As [(wvM * 64 + i * 16 + l15) * LDSS + kc * 32 + quad * 8];
                bF[i] = *(const bf16x8*)&Bsh[(wvN * 64 + i * 16 + l15) * LDSS + kc * 32 + quad * 8];
            }
            #pragma unroll
            for (int mi = 0; mi < 4; ++mi)
                #pragma unroll
                for (int ni = 0; ni < 4; ++ni)
                    acc[mi][ni] = __builtin_amdgcn_mfma_f32_16x16x32_bf16(
                        aF[mi], bF[ni], acc[mi][ni], 0, 0, 0);
        }
    }

    // Epilogue: per output v (cosine): es += exp2((v-1)*20*log2e); packed argmax.
    const float C20 = 28.853900817779268f;  // 20*log2(e)
    const int chunk = nTile * 2 + wvN;
    #pragma unroll
    for (int mi = 0; mi < 4; ++mi) {
        float    es[4] = {0.f, 0.f, 0.f, 0.f};
        unsigned km[4] = {0u, 0u, 0u, 0u};
        #pragma unroll
        for (int ni = 0; ni < 4; ++ni) {
            const int col = nTile * 128 + wvN * 64 + ni * 16 + l15;
            const unsigned colenc = 2047u - (unsigned)col;
            const bool valid = (col < NC);
            #pragma unroll
            for (int r = 0; r < 4; ++r) {
                float v = valid ? acc[mi][ni][r] : -3.0f;
                es[r] += exp2f((v - 1.0f) * C20);
                unsigned u = __float_as_uint(v);
                unsigned k = u ^ (unsigned)(((int)u >> 31) | 0x80000000);
                unsigned pk = (k & 0xFFFFF800u) | colenc;  // bigger v, then smaller col
                km[r] = pk > km[r] ? pk : km[r];
            }
        }
        #pragma unroll
        for (int r = 0; r < 4; ++r) {
            #pragma unroll
            for (int m = 1; m < 16; m <<= 1) {
                es[r] += __shfl_xor(es[r], m, 64);
                unsigned x = __shfl_xor(km[r], m, 64);
                km[r] = x > km[r] ? x : km[r];
            }
        }
        if (l15 == 0) {
            #pragma unroll
            for (int r = 0; r < 4; ++r) {
                const int row = mTile * 128 + wvM * 64 + mi * 16 + quad * 4 + r;
                es_part [chunk * BS + row] = es[r];
                key_part[chunk * BS + row] = km[r];
            }
        }
    }
}

// ---------------------------------------------------------------------------
// Kernel 3: gather pred[i,label[i]] and sum_j pred[i,aux[i,j]]. One wave/row.
// ---------------------------------------------------------------------------
__global__ __launch_bounds__(256) void gather_kernel(
    const __bf16* __restrict__ fn, const __bf16* __restrict__ wn,
    const int* __restrict__ label, const int* __restrict__ aux,
    float* __restrict__ tgt, float* __restrict__ auxs)
{
    const int lane = threadIdx.x & 63;
    const int row  = blockIdx.x * 4 + (threadIdx.x >> 6);

    bf16x8 f8 = *((const bf16x8*)fn + (size_t)row * (EMB / 8) + lane);
    float fv[8];
    #pragma unroll
    for (int j = 0; j < 8; ++j) fv[j] = (float)f8[j];

    int cols[6];
    cols[0] = label[row];
    #pragma unroll
    for (int j = 0; j < NAUX; ++j) cols[j + 1] = aux[row * NAUX + j];

    float res[6];
    #pragma unroll
    for (int c = 0; c < 6; ++c) {
        bf16x8 w8 = *((const bf16x8*)wn + (size_t)cols[c] * (EMB / 8) + lane);
        float d = 0.f;
        #pragma unroll
        for (int j = 0; j < 8; ++j) d += fv[j] * (float)w8[j];
        #pragma unroll
        for (int m = 1; m < 64; m <<= 1) d += __shfl_xor(d, m, 64);
        res[c] = d;
    }
    if (lane == 0) {
        tgt[row]  = res[0] * 20.0f;
        auxs[row] = (res[1] + res[2] + res[3] + res[4] + res[5]) * 20.0f;
    }
}

// ---------------------------------------------------------------------------
// Kernel 4: combine 32 chunk partials per row -> loss_i, acc_i; block-reduce.
// loss_i = 20 + log(es) - 0.95*tgt_i - 0.01*auxsum_i
// ---------------------------------------------------------------------------
__global__ __launch_bounds__(256) void fin1_kernel(
    const float* __restrict__ es_part, const unsigned* __restrict__ key_part,
    const float* __restrict__ tgt, const float* __restrict__ auxs,
    const int* __restrict__ label, float* __restrict__ blk)
{
    const int row = blockIdx.x * 256 + threadIdx.x;
    float es = 0.f;
    unsigned k = 0u;
    #pragma unroll
    for (int c = 0; c < NCHUNK; ++c) {
        es += es_part[c * BS + row];
        unsigned x = key_part[c * BS + row];
        k = x > k ? x : k;
    }
    const int amax = 2047 - (int)(k & 0x7FFu);

    float loss = 20.0f + logf(es) - 0.95f * tgt[row] - 0.01f * auxs[row];
    float acc  = (amax == label[row]) ? 1.0f : 0.0f;

    #pragma unroll
    for (int m = 1; m < 64; m <<= 1) {
        loss += __shfl_xor(loss, m, 64);
        acc  += __shfl_xor(acc, m, 64);
    }
    __shared__ float sl[4], sa[4];
    const int wv = threadIdx.x >> 6;
    if ((threadIdx.x & 63) == 0) { sl[wv] = loss; sa[wv] = acc; }
    __syncthreads();
    if (threadIdx.x == 0) {
        blk[blockIdx.x]      = sl[0] + sl[1] + sl[2] + sl[3];
        blk[64 + blockIdx.x] = sa[0] + sa[1] + sa[2] + sa[3];
    }
}

__global__ __launch_bounds__(64) void fin2_kernel(
    const float* __restrict__ blk, float* __restrict__ out)
{
    float l = blk[threadIdx.x];
    float a = blk[64 + threadIdx.x];
    #pragma unroll
    for (int m = 1; m < 64; m <<= 1) {
        l += __shfl_xor(l, m, 64);
        a += __shfl_xor(a, m, 64);
    }
    if (threadIdx.x == 0) {
        out[0] = l / (float)BS;
        out[1] = a / (float)BS;
    }
}

// ---------------------------------------------------------------------------
// Workspace layout (bytes):
//   fn   @ 0         (16,777,216)  BS x 512 bf16
//   wn   @ 16777216  ( 2,097,152)  NCP(2048) x 512 bf16 (rows >=2000 zero)
//   es   @ 18874368  ( 2,097,152)  [32][BS] f32
//   key  @ 20971520  ( 2,097,152)  [32][BS] u32
//   tgt  @ 23068672  (    65,536)
//   auxs @ 23134208  (    65,536)
//   blk  @ 23199744  (       512)
// ---------------------------------------------------------------------------
extern "C" void kernel_launch(void* const* d_in, const int* in_sizes, int n_in,
                              void* d_out, int out_size, void* d_ws, size_t ws_size,
                              hipStream_t stream)
{
    const float* feat  = (const float*)d_in[0];
    const float* wemb  = (const float*)d_in[1];
    const int*   label = (const int*)d_in[2];
    const int*   aux   = (const int*)d_in[3];

    char* ws = (char*)d_ws;
    __bf16*   fn   = (__bf16*)(ws);
    __bf16*   wn   = (__bf16*)(ws + 16777216);
    float*    es   = (float*)(ws + 18874368);
    unsigned* key  = (unsigned*)(ws + 20971520);
    float*    tgt  = (float*)(ws + 23068672);
    float*    auxs = (float*)(ws + 23134208);
    float*    blk  = (float*)(ws + 23199744);
    float*    out  = (float*)d_out;

    hipLaunchKernelGGL(norm_kernel, dim3((BS + NCP) / 4), dim3(256), 0, stream,
                       feat, wemb, fn, wn);
    hipLaunchKernelGGL(main_kernel, dim3((BS / 128) * (NCP / 128)), dim3(256), 0, stream,
                       fn, wn, es, key);
    hipLaunchKernelGGL(gather_kernel, dim3(BS / 4), dim3(256), 0, stream,
                       fn, wn, label, aux, tgt, auxs);
    hipLaunchKernelGGL(fin1_kernel, dim3(BS / 256), dim3(256), 0, stream,
                       es, key, tgt, auxs, label, blk);
    hipLaunchKernelGGL(fin2_kernel, dim3(1), dim3(64), 0, stream, blk, out);
}